// Round 10
// baseline (129.985 us; speedup 1.0000x reference)
//
#include <hip/hip_runtime.h>
#include <math.h>

#define FFT_N   4096
#define THREADS 256
#define PADN    4384   // max pad index 4377 complex slots

// Complex-interleaved LDS (float2) with 3-term additive pad:
//   p(i) = i + 4*(i>>6) + 2*(i>>8)   (monotone -> bijective)
// Byte-bank analysis (b64 pair-group = p&15, b128 quad-group = (byte>>4)&7):
//  A (i=t+256k):    p = [t+4*(t>>6)] + 274k        linear; 4 lanes/pair  (free)
//  B (i=256a+j+16k):p = [274a+j] + 16k+4*(k>>2)    linear; 4 lanes/pair  (free)
//  C (i=16t+n):     p = [16t+4*(t>>2)+2*(t>>4)]+n  contiguous, 16B-aligned;
//                   8 lanes/quad -> conflict-free ds_*_b128
// All per-k offsets fold into ds imm offsets -> zero per-access VALU.

// rev4: base-4 digit reversal within 16 (self-inverse). In-place DIF dft16
// leaves slot r holding spectral index REV[r]; all uses are compile-time.
#define REV(r) ((((r) & 3) << 2) | ((r) >> 2))

// gperm[16t + r] = G at local position 16t + REV(r),
// G(p) = ((W[k]+W[(N-k)%N])/2 + 1)/N, k = 3-digit base-16 reversal of p.
__global__ void setup_g_kernel(const float* __restrict__ fw, float* __restrict__ gperm) {
    int p = blockIdx.x * blockDim.x + threadIdx.x;
    if (p >= FFT_N) return;
    int r = p & 15;
    int local = (p & ~15) | REV(r);
    unsigned k = ((local & 15u) << 8) | ((unsigned)local & 0xF0u) | ((unsigned)local >> 8);
    float wk  = fw[k];
    float wnk = fw[(FFT_N - k) & (FFT_N - 1)];
    gperm[p] = (0.5f * (wk + wnk) + 1.0f) * (1.0f / (float)FFT_N);
}

__device__ __forceinline__ void cmul(float& xr, float& xi, float c, float s) {
    float tv = xr; xr = tv * c - xi * s; xi = tv * s + xi * c;
}

// forward radix-4 butterfly, in place: X1 = t1 - i*t3, X3 = t1 + i*t3
__device__ __forceinline__ void bfly4_f(float& ar, float& ai, float& br, float& bi,
                                        float& cr, float& ci, float& dr, float& di) {
    float t0r = ar + cr, t0i = ai + ci;
    float t1r = ar - cr, t1i = ai - ci;
    float t2r = br + dr, t2i = bi + di;
    float t3r = br - dr, t3i = bi - di;
    ar = t0r + t2r; ai = t0i + t2i;
    br = t1r + t3i; bi = t1i - t3r;
    cr = t0r - t2r; ci = t0i - t2i;
    dr = t1r - t3i; di = t1i + t3r;
}
// inverse radix-4 butterfly, in place: Y1 = t1 + i*t3, Y3 = t1 - i*t3
__device__ __forceinline__ void bfly4_i(float& ar, float& ai, float& br, float& bi,
                                        float& cr, float& ci, float& dr, float& di) {
    float t0r = ar + cr, t0i = ai + ci;
    float t1r = ar - cr, t1i = ai - ci;
    float t2r = br + dr, t2i = bi + di;
    float t3r = br - dr, t3i = bi - di;
    ar = t0r + t2r; ai = t0i + t2i;
    br = t1r - t3i; bi = t1i + t3r;
    cr = t0r - t2r; ci = t0i - t2i;
    dr = t1r + t3i; di = t1i - t3r;
}

// In-place forward DFT16 (DIF). Output: slot r holds X[REV(r)].
__device__ __forceinline__ void dft16_f(float xr[16], float xi[16]) {
    const float C1 = 0.9238795325112867f;   // cos(pi/8)
    const float S1 = 0.3826834323650898f;   // sin(pi/8)
    const float H  = 0.7071067811865476f;
    #pragma unroll
    for (int m = 0; m < 4; ++m)
        bfly4_f(xr[m],xi[m], xr[m+4],xi[m+4], xr[m+8],xi[m+8], xr[m+12],xi[m+12]);
    cmul(xr[5],  xi[5],   C1, -S1);
    cmul(xr[9],  xi[9],    H,  -H);
    cmul(xr[13], xi[13],  S1, -C1);
    cmul(xr[6],  xi[6],    H,  -H);
    cmul(xr[10], xi[10], 0.f, -1.f);
    cmul(xr[14], xi[14],  -H,  -H);
    cmul(xr[7],  xi[7],   S1, -C1);
    cmul(xr[11], xi[11],  -H,  -H);
    cmul(xr[15], xi[15], -C1,  S1);
    #pragma unroll
    for (int g = 0; g < 4; ++g)
        bfly4_f(xr[4*g],xi[4*g], xr[4*g+1],xi[4*g+1], xr[4*g+2],xi[4*g+2], xr[4*g+3],xi[4*g+3]);
}

// In-place inverse DFT16 (unnormalized). Input: slot r holds X[REV(r)].
// Output: slot n holds x[n] (natural).
__device__ __forceinline__ void idft16(float xr[16], float xi[16]) {
    const float C1 = 0.9238795325112867f;
    const float S1 = 0.3826834323650898f;
    const float H  = 0.7071067811865476f;
    #pragma unroll
    for (int g = 0; g < 4; ++g)
        bfly4_i(xr[4*g],xi[4*g], xr[4*g+1],xi[4*g+1], xr[4*g+2],xi[4*g+2], xr[4*g+3],xi[4*g+3]);
    cmul(xr[5],  xi[5],   C1,  S1);
    cmul(xr[9],  xi[9],    H,   H);
    cmul(xr[13], xi[13],  S1,  C1);
    cmul(xr[6],  xi[6],    H,   H);
    cmul(xr[10], xi[10], 0.f, 1.f);
    cmul(xr[14], xi[14],  -H,   H);
    cmul(xr[7],  xi[7],   S1,  C1);
    cmul(xr[11], xi[11],  -H,   H);
    cmul(xr[15], xi[15], -C1, -S1);
    #pragma unroll
    for (int m = 0; m < 4; ++m)
        bfly4_i(xr[m],xi[m], xr[m+4],xi[m+4], xr[m+8],xi[m+8], xr[m+12],xi[m+12]);
}

// apply w^{REV(r)} to slot r (i.e. power p -> slot REV(p)); binary-power
// chain, dependency depth ~5. w = (cos ang, sin ang).
__device__ __forceinline__ void twiddle_rev(float xr[16], float xi[16], float ang) {
    float s1, c1; __sincosf(ang, &s1, &c1);
    float c2 = c1*c1 - s1*s1, s2 = 2.f*c1*s1;
    float c3 = c2*c1 - s2*s1, s3 = c2*s1 + s2*c1;
    float c4 = c2*c2 - s2*s2, s4 = 2.f*c2*s2;
    cmul(xr[4],  xi[4],  c1, s1);
    cmul(xr[8],  xi[8],  c2, s2);
    cmul(xr[12], xi[12], c3, s3);
    float bc = c4, bs = s4;
    #pragma unroll
    for (int q = 1; q < 4; ++q) {
        cmul(xr[q], xi[q], bc, bs);
        { float ec = bc*c1 - bs*s1, es = bc*s1 + bs*c1; cmul(xr[4+q],  xi[4+q],  ec, es); }
        { float ec = bc*c2 - bs*s2, es = bc*s2 + bs*c2; cmul(xr[8+q],  xi[8+q],  ec, es); }
        { float ec = bc*c3 - bs*s3, es = bc*s3 + bs*c3; cmul(xr[12+q], xi[12+q], ec, es); }
        if (q < 3) { float nb = bc*c4 - bs*s4; bs = bc*s4 + bs*c4; bc = nb; }
    }
}

__global__ __launch_bounds__(THREADS, 4) void fourier_fft_kernel(
    const float* __restrict__ in, const float* __restrict__ gperm,
    const float* __restrict__ lw, float* __restrict__ out)
{
    __shared__ float2 sh[PADN];
    const int t = threadIdx.x;
    const long long pair = blockIdx.x;
    const float* r0 = in + pair * (2LL * FFT_N);
    const float* r1 = r0 + FFT_N;

    const float CFA = -6.28318530717958647692f / 4096.0f;
    const float CFB = -6.28318530717958647692f / 256.0f;

    // per-thread LDS bases (all per-k offsets are compile-time immediates)
    const int baseA = t + 4 * (t >> 6);                         // + 274k
    const int baseB = 274 * (t >> 4) + (t & 15);                // + 16k + 4*(k>>2)
    const int baseC = 16 * t + 4 * (t >> 2) + 2 * (t >> 4);     // + n (16B-aligned)
    const int jb = t & 15;

    float xr[16], xi[16];

    // load: thread t owns x[t + 256n] — coalesced
    #pragma unroll
    for (int n = 0; n < 16; ++n) {
        xr[n] = r0[t + 256*n];
        xi[n] = r1[t + 256*n];
    }

    // ---- forward stage A (L=4096, j=t): slot r holds A[REV(r)]
    dft16_f(xr, xi);
    twiddle_rev(xr, xi, CFA * (float)t);
    #pragma unroll
    for (int k = 0; k < 16; ++k)
        sh[baseA + 274*k] = make_float2(xr[REV(k)], xi[REV(k)]);
    __syncthreads();

    // ---- forward stage B (L=256, j=t&15)
    #pragma unroll
    for (int n = 0; n < 16; ++n) {
        float2 v = sh[baseB + 16*n + 4*(n>>2)];
        xr[n] = v.x; xi[n] = v.y;
    }
    dft16_f(xr, xi);
    twiddle_rev(xr, xi, CFB * (float)jb);
    #pragma unroll
    for (int k = 0; k < 16; ++k)
        sh[baseB + 16*k + 4*(k>>2)] = make_float2(xr[REV(k)], xi[REV(k)]);
    __syncthreads();

    // ---- forward stage C + pointwise G + inverse stage C', all in registers.
    // contiguous 16 complex -> 8x ds_read_b128 / 8x ds_write_b128
    #pragma unroll
    for (int q = 0; q < 8; ++q) {
        float4 v = *(const float4*)&sh[baseC + 2*q];
        xr[2*q+0] = v.x; xi[2*q+0] = v.y;
        xr[2*q+1] = v.z; xi[2*q+1] = v.w;
    }
    dft16_f(xr, xi);
    {
        const float4* gp = (const float4*)(gperm + 16*t);   // already REV-permuted
        #pragma unroll
        for (int q = 0; q < 4; ++q) {
            float4 g = gp[q];
            xr[4*q+0] *= g.x; xi[4*q+0] *= g.x;
            xr[4*q+1] *= g.y; xi[4*q+1] *= g.y;
            xr[4*q+2] *= g.z; xi[4*q+2] *= g.z;
            xr[4*q+3] *= g.w; xi[4*q+3] *= g.w;
        }
    }
    idft16(xr, xi);
    #pragma unroll
    for (int q = 0; q < 8; ++q) {
        *(float4*)&sh[baseC + 2*q] =
            make_float4(xr[2*q+0], xi[2*q+0], xr[2*q+1], xi[2*q+1]);
    }
    __syncthreads();

    // ---- inverse stage B': load digit-reversed, conj twiddle, idft16
    #pragma unroll
    for (int k = 0; k < 16; ++k) {
        float2 v = sh[baseB + 16*k + 4*(k>>2)];
        xr[REV(k)] = v.x; xi[REV(k)] = v.y;
    }
    twiddle_rev(xr, xi, -CFB * (float)jb);
    idft16(xr, xi);
    #pragma unroll
    for (int n = 0; n < 16; ++n)
        sh[baseB + 16*n + 4*(n>>2)] = make_float2(xr[n], xi[n]);
    __syncthreads();

    // ---- inverse stage A' + epilogue straight from registers
    #pragma unroll
    for (int k = 0; k < 16; ++k) {
        float2 v = sh[baseA + 274*k];
        xr[REV(k)] = v.x; xi[REV(k)] = v.y;
    }
    twiddle_rev(xr, xi, -CFA * (float)t);
    idft16(xr, xi);

    float* o0 = out + pair * (2LL * FFT_N);
    #pragma unroll
    for (int n = 0; n < 16; ++n) {
        int i = t + 256*n;
        float l = lw[i];
        o0[i]         = fmaxf(xr[n]*l, 0.0f);
        o0[FFT_N + i] = fmaxf(xi[n]*l, 0.0f);
    }
}

extern "C" void kernel_launch(void* const* d_in, const int* in_sizes, int n_in,
                              void* d_out, int out_size, void* d_ws, size_t ws_size,
                              hipStream_t stream) {
    const float* inputs = (const float*)d_in[0];
    const float* fw     = (const float*)d_in[1];
    const float* lw     = (const float*)d_in[2];
    float* out   = (float*)d_out;
    float* gperm = (float*)d_ws;   // 4096 floats = 16 KB scratch

    hipLaunchKernelGGL(setup_g_kernel, dim3(FFT_N / THREADS), dim3(THREADS), 0, stream,
                       fw, gperm);

    const int pairs = in_sizes[0] / (2 * FFT_N);   // 16384 rows -> 8192 pairs
    hipLaunchKernelGGL(fourier_fft_kernel, dim3(pairs), dim3(THREADS), 0, stream,
                       inputs, gperm, lw, out);
}

// Round 11
// 119.547 us; speedup vs baseline: 1.0873x; 1.0873x over previous
//
#include <hip/hip_runtime.h>
#include <math.h>

#define FFT_N   4096
#define THREADS 256
#define PADN    4352   // max slot 4347

// ONE layout for the whole kernel:
//   p = 256*hi + lo,  lo = j + 16k  (j<16, k<16)
//   L(p) = 272*hi + 16*j + 4*(j>>2) + k
// Per-stage per-thread slot sets (read set == write set -> in-place, no
// extra barriers):
//  A-write  (p=t+256kA):   slot = [16(t&15)+4((t&15)>>2)+(t>>4)] + 272*kA   b32 x16, 2-way
//  B r/w    (p=256a+j+16k): slot = [272a+16j+4(j>>2)] + k  CONTIGUOUS      b128 x4 each
//  C r/w    (p=16t+n):      slot = [272(t>>4)+(t&15)] + 16n+4(n>>2)        b32 x16, 2-way
//  B' r/w   = B pattern                                                    b128 x4 each
//  A'-read  = A pattern                                                    b32 x16, 2-way
// All per-k offsets are compile-time immediates -> ~zero address VALU.

// rev4: base-4 digit reversal within 16 (self-inverse), compile-time only.
#define REV(r) ((((r) & 3) << 2) | ((r) >> 2))

// gperm[16t + r] = G at local position 16t + REV(r),
// G(p) = ((W[k]+W[(N-k)%N])/2 + 1)/N, k = 3-digit base-16 reversal of p.
__global__ void setup_g_kernel(const float* __restrict__ fw, float* __restrict__ gperm) {
    int p = blockIdx.x * blockDim.x + threadIdx.x;
    if (p >= FFT_N) return;
    int r = p & 15;
    int local = (p & ~15) | REV(r);
    unsigned k = ((local & 15u) << 8) | ((unsigned)local & 0xF0u) | ((unsigned)local >> 8);
    float wk  = fw[k];
    float wnk = fw[(FFT_N - k) & (FFT_N - 1)];
    gperm[p] = (0.5f * (wk + wnk) + 1.0f) * (1.0f / (float)FFT_N);
}

__device__ __forceinline__ void cmul(float& xr, float& xi, float c, float s) {
    float tv = xr; xr = tv * c - xi * s; xi = tv * s + xi * c;
}

// forward radix-4 butterfly, in place: X1 = t1 - i*t3, X3 = t1 + i*t3
__device__ __forceinline__ void bfly4_f(float& ar, float& ai, float& br, float& bi,
                                        float& cr, float& ci, float& dr, float& di) {
    float t0r = ar + cr, t0i = ai + ci;
    float t1r = ar - cr, t1i = ai - ci;
    float t2r = br + dr, t2i = bi + di;
    float t3r = br - dr, t3i = bi - di;
    ar = t0r + t2r; ai = t0i + t2i;
    br = t1r + t3i; bi = t1i - t3r;
    cr = t0r - t2r; ci = t0i - t2i;
    dr = t1r - t3i; di = t1i + t3r;
}
// inverse radix-4 butterfly, in place: Y1 = t1 + i*t3, Y3 = t1 - i*t3
__device__ __forceinline__ void bfly4_i(float& ar, float& ai, float& br, float& bi,
                                        float& cr, float& ci, float& dr, float& di) {
    float t0r = ar + cr, t0i = ai + ci;
    float t1r = ar - cr, t1i = ai - ci;
    float t2r = br + dr, t2i = bi + di;
    float t3r = br - dr, t3i = bi - di;
    ar = t0r + t2r; ai = t0i + t2i;
    br = t1r - t3i; bi = t1i + t3r;
    cr = t0r - t2r; ci = t0i - t2i;
    dr = t1r + t3i; di = t1i - t3r;
}

// In-place forward DFT16 (DIF). Output: slot r holds X[REV(r)].
__device__ __forceinline__ void dft16_f(float xr[16], float xi[16]) {
    const float C1 = 0.9238795325112867f;   // cos(pi/8)
    const float S1 = 0.3826834323650898f;   // sin(pi/8)
    const float H  = 0.7071067811865476f;
    #pragma unroll
    for (int m = 0; m < 4; ++m)
        bfly4_f(xr[m],xi[m], xr[m+4],xi[m+4], xr[m+8],xi[m+8], xr[m+12],xi[m+12]);
    cmul(xr[5],  xi[5],   C1, -S1);
    cmul(xr[9],  xi[9],    H,  -H);
    cmul(xr[13], xi[13],  S1, -C1);
    cmul(xr[6],  xi[6],    H,  -H);
    cmul(xr[10], xi[10], 0.f, -1.f);
    cmul(xr[14], xi[14],  -H,  -H);
    cmul(xr[7],  xi[7],   S1, -C1);
    cmul(xr[11], xi[11],  -H,  -H);
    cmul(xr[15], xi[15], -C1,  S1);
    #pragma unroll
    for (int g = 0; g < 4; ++g)
        bfly4_f(xr[4*g],xi[4*g], xr[4*g+1],xi[4*g+1], xr[4*g+2],xi[4*g+2], xr[4*g+3],xi[4*g+3]);
}

// In-place inverse DFT16 (unnormalized). Input: slot r holds X[REV(r)].
// Output: slot n holds x[n] (natural).
__device__ __forceinline__ void idft16(float xr[16], float xi[16]) {
    const float C1 = 0.9238795325112867f;
    const float S1 = 0.3826834323650898f;
    const float H  = 0.7071067811865476f;
    #pragma unroll
    for (int g = 0; g < 4; ++g)
        bfly4_i(xr[4*g],xi[4*g], xr[4*g+1],xi[4*g+1], xr[4*g+2],xi[4*g+2], xr[4*g+3],xi[4*g+3]);
    cmul(xr[5],  xi[5],   C1,  S1);
    cmul(xr[9],  xi[9],    H,   H);
    cmul(xr[13], xi[13],  S1,  C1);
    cmul(xr[6],  xi[6],    H,   H);
    cmul(xr[10], xi[10], 0.f, 1.f);
    cmul(xr[14], xi[14],  -H,   H);
    cmul(xr[7],  xi[7],   S1,  C1);
    cmul(xr[11], xi[11],  -H,   H);
    cmul(xr[15], xi[15], -C1, -S1);
    #pragma unroll
    for (int m = 0; m < 4; ++m)
        bfly4_i(xr[m],xi[m], xr[m+4],xi[m+4], xr[m+8],xi[m+8], xr[m+12],xi[m+12]);
}

// apply w^{REV(r)} to slot r; binary-power chain, dependency depth ~5.
__device__ __forceinline__ void twiddle_rev(float xr[16], float xi[16], float ang) {
    float s1, c1; __sincosf(ang, &s1, &c1);
    float c2 = c1*c1 - s1*s1, s2 = 2.f*c1*s1;
    float c3 = c2*c1 - s2*s1, s3 = c2*s1 + s2*c1;
    float c4 = c2*c2 - s2*s2, s4 = 2.f*c2*s2;
    cmul(xr[4],  xi[4],  c1, s1);
    cmul(xr[8],  xi[8],  c2, s2);
    cmul(xr[12], xi[12], c3, s3);
    float bc = c4, bs = s4;
    #pragma unroll
    for (int q = 1; q < 4; ++q) {
        cmul(xr[q], xi[q], bc, bs);
        { float ec = bc*c1 - bs*s1, es = bc*s1 + bs*c1; cmul(xr[4+q],  xi[4+q],  ec, es); }
        { float ec = bc*c2 - bs*s2, es = bc*s2 + bs*c2; cmul(xr[8+q],  xi[8+q],  ec, es); }
        { float ec = bc*c3 - bs*s3, es = bc*s3 + bs*c3; cmul(xr[12+q], xi[12+q], ec, es); }
        if (q < 3) { float nb = bc*c4 - bs*s4; bs = bc*s4 + bs*c4; bc = nb; }
    }
}

__global__ __launch_bounds__(THREADS, 4) void fourier_fft_kernel(
    const float* __restrict__ in, const float* __restrict__ gperm,
    const float* __restrict__ lw, float* __restrict__ out)
{
    __shared__ __align__(16) float re[PADN];
    __shared__ __align__(16) float im[PADN];
    const int t = threadIdx.x;
    const long long pair = blockIdx.x;
    const float* r0 = in + pair * (2LL * FFT_N);
    const float* r1 = r0 + FFT_N;

    const float CFA = -6.28318530717958647692f / 4096.0f;
    const float CFB = -6.28318530717958647692f / 256.0f;

    const int jt = t & 15, ht = t >> 4;
    const int baseL = 16*jt + 4*(jt>>2) + ht;          // A-write / A'-read, +272k
    const int baseB = 272*ht + 16*jt + 4*(jt>>2);      // B/B' r+w, contiguous 16
    const int baseC = 272*ht + jt;                     // C r/w, +16n+4*(n>>2)

    float xr[16], xi[16];

    // load: thread t owns x[t + 256n] — coalesced
    #pragma unroll
    for (int n = 0; n < 16; ++n) {
        xr[n] = r0[t + 256*n];
        xi[n] = r1[t + 256*n];
    }

    // ---- forward stage A (L=4096, j=t): slot r holds A[REV(r)]
    dft16_f(xr, xi);
    twiddle_rev(xr, xi, CFA * (float)t);
    #pragma unroll
    for (int k = 0; k < 16; ++k) {
        re[baseL + 272*k] = xr[REV(k)];
        im[baseL + 272*k] = xi[REV(k)];
    }
    __syncthreads();

    // ---- forward stage B (L=256, j=jt): contiguous b128 read AND write (in-place)
    #pragma unroll
    for (int q = 0; q < 4; ++q) {
        float4 vr = *(const float4*)&re[baseB + 4*q];
        float4 vi = *(const float4*)&im[baseB + 4*q];
        xr[4*q+0] = vr.x; xr[4*q+1] = vr.y; xr[4*q+2] = vr.z; xr[4*q+3] = vr.w;
        xi[4*q+0] = vi.x; xi[4*q+1] = vi.y; xi[4*q+2] = vi.z; xi[4*q+3] = vi.w;
    }
    dft16_f(xr, xi);
    twiddle_rev(xr, xi, CFB * (float)jt);
    #pragma unroll
    for (int q = 0; q < 4; ++q) {
        // slot base+4q+m holds X[4q+m] which lives in register REV(4q+m)=4m+q
        *(float4*)&re[baseB + 4*q] = make_float4(xr[q], xr[4+q], xr[8+q], xr[12+q]);
        *(float4*)&im[baseB + 4*q] = make_float4(xi[q], xi[4+q], xi[8+q], xi[12+q]);
    }
    __syncthreads();

    // ---- forward stage C + pointwise G + inverse stage C' (in-place scatter)
    #pragma unroll
    for (int n = 0; n < 16; ++n) {
        int s = baseC + 16*n + 4*(n>>2);
        xr[n] = re[s]; xi[n] = im[s];
    }
    dft16_f(xr, xi);
    {
        const float4* gp = (const float4*)(gperm + 16*t);   // already REV-permuted
        #pragma unroll
        for (int q = 0; q < 4; ++q) {
            float4 g = gp[q];
            xr[4*q+0] *= g.x; xi[4*q+0] *= g.x;
            xr[4*q+1] *= g.y; xi[4*q+1] *= g.y;
            xr[4*q+2] *= g.z; xi[4*q+2] *= g.z;
            xr[4*q+3] *= g.w; xi[4*q+3] *= g.w;
        }
    }
    idft16(xr, xi);
    #pragma unroll
    for (int n = 0; n < 16; ++n) {
        int s = baseC + 16*n + 4*(n>>2);
        re[s] = xr[n]; im[s] = xi[n];
    }
    __syncthreads();

    // ---- inverse stage B': contiguous b128 read, conj twiddle, idft16, b128 write
    #pragma unroll
    for (int q = 0; q < 4; ++q) {
        float4 vr = *(const float4*)&re[baseB + 4*q];
        float4 vi = *(const float4*)&im[baseB + 4*q];
        // point digit k=4q+m goes to register REV(4q+m)=4m+q
        xr[q] = vr.x; xr[4+q] = vr.y; xr[8+q] = vr.z; xr[12+q] = vr.w;
        xi[q] = vi.x; xi[4+q] = vi.y; xi[8+q] = vi.z; xi[12+q] = vi.w;
    }
    twiddle_rev(xr, xi, -CFB * (float)jt);
    idft16(xr, xi);
    #pragma unroll
    for (int q = 0; q < 4; ++q) {
        *(float4*)&re[baseB + 4*q] = make_float4(xr[4*q+0], xr[4*q+1], xr[4*q+2], xr[4*q+3]);
        *(float4*)&im[baseB + 4*q] = make_float4(xi[4*q+0], xi[4*q+1], xi[4*q+2], xi[4*q+3]);
    }
    __syncthreads();

    // ---- inverse stage A' + epilogue straight from registers
    #pragma unroll
    for (int k = 0; k < 16; ++k) {
        xr[REV(k)] = re[baseL + 272*k];
        xi[REV(k)] = im[baseL + 272*k];
    }
    twiddle_rev(xr, xi, -CFA * (float)t);
    idft16(xr, xi);

    float* o0 = out + pair * (2LL * FFT_N);
    #pragma unroll
    for (int n = 0; n < 16; ++n) {
        int i = t + 256*n;
        float l = lw[i];
        o0[i]         = fmaxf(xr[n]*l, 0.0f);
        o0[FFT_N + i] = fmaxf(xi[n]*l, 0.0f);
    }
}

extern "C" void kernel_launch(void* const* d_in, const int* in_sizes, int n_in,
                              void* d_out, int out_size, void* d_ws, size_t ws_size,
                              hipStream_t stream) {
    const float* inputs = (const float*)d_in[0];
    const float* fw     = (const float*)d_in[1];
    const float* lw     = (const float*)d_in[2];
    float* out   = (float*)d_out;
    float* gperm = (float*)d_ws;   // 4096 floats = 16 KB scratch

    hipLaunchKernelGGL(setup_g_kernel, dim3(FFT_N / THREADS), dim3(THREADS), 0, stream,
                       fw, gperm);

    const int pairs = in_sizes[0] / (2 * FFT_N);   // 16384 rows -> 8192 pairs
    hipLaunchKernelGGL(fourier_fft_kernel, dim3(pairs), dim3(THREADS), 0, stream,
                       inputs, gperm, lw, out);
}

// Round 12
// 116.574 us; speedup vs baseline: 1.1150x; 1.0255x over previous
//
#include <hip/hip_runtime.h>
#include <math.h>

#define FFT_N   4096
#define THREADS 256
#define PADN    4352   // max pad4 index 4347

// Additive pad: pad4(i) = i + 4*(i>>6)  (R9 champion layout).
//  A (i=t+256k):    base [t+4*(t>>6)] + 272k        linear -> ds imm, 2-way banks
//  B (i=256a+j+16k): base [272a+j] + 16k+4*(k>>2)   linear -> ds imm, 2-way banks
//  C (i=16t+n):     base [16t+4*(t>>2)] + n         contiguous 16B-aligned -> b128
// Global streams split into 4 base pointers each so every global offset fits
// the 13-bit immediate (4096*n bytes > 4095 would burn an address pair per load).

#define REV(r) ((((r) & 3) << 2) | ((r) >> 2))

// gperm[16t + r] = G at local position 16t + REV(r),
// G(p) = ((W[k]+W[(N-k)%N])/2 + 1)/N, k = 3-digit base-16 reversal of p.
__global__ void setup_g_kernel(const float* __restrict__ fw, float* __restrict__ gperm) {
    int p = blockIdx.x * blockDim.x + threadIdx.x;
    if (p >= FFT_N) return;
    int r = p & 15;
    int local = (p & ~15) | REV(r);
    unsigned k = ((local & 15u) << 8) | ((unsigned)local & 0xF0u) | ((unsigned)local >> 8);
    float wk  = fw[k];
    float wnk = fw[(FFT_N - k) & (FFT_N - 1)];
    gperm[p] = (0.5f * (wk + wnk) + 1.0f) * (1.0f / (float)FFT_N);
}

__device__ __forceinline__ void cmul(float& xr, float& xi, float c, float s) {
    float tv = xr; xr = tv * c - xi * s; xi = tv * s + xi * c;
}

__device__ __forceinline__ void bfly4_f(float& ar, float& ai, float& br, float& bi,
                                        float& cr, float& ci, float& dr, float& di) {
    float t0r = ar + cr, t0i = ai + ci;
    float t1r = ar - cr, t1i = ai - ci;
    float t2r = br + dr, t2i = bi + di;
    float t3r = br - dr, t3i = bi - di;
    ar = t0r + t2r; ai = t0i + t2i;
    br = t1r + t3i; bi = t1i - t3r;
    cr = t0r - t2r; ci = t0i - t2i;
    dr = t1r - t3i; di = t1i + t3r;
}
__device__ __forceinline__ void bfly4_i(float& ar, float& ai, float& br, float& bi,
                                        float& cr, float& ci, float& dr, float& di) {
    float t0r = ar + cr, t0i = ai + ci;
    float t1r = ar - cr, t1i = ai - ci;
    float t2r = br + dr, t2i = bi + di;
    float t3r = br - dr, t3i = bi - di;
    ar = t0r + t2r; ai = t0i + t2i;
    br = t1r - t3i; bi = t1i + t3r;
    cr = t0r - t2r; ci = t0i - t2i;
    dr = t1r + t3i; di = t1i - t3r;
}

// In-place forward DFT16 (DIF). Output: slot r holds X[REV(r)].
__device__ __forceinline__ void dft16_f(float xr[16], float xi[16]) {
    const float C1 = 0.9238795325112867f;
    const float S1 = 0.3826834323650898f;
    const float H  = 0.7071067811865476f;
    #pragma unroll
    for (int m = 0; m < 4; ++m)
        bfly4_f(xr[m],xi[m], xr[m+4],xi[m+4], xr[m+8],xi[m+8], xr[m+12],xi[m+12]);
    cmul(xr[5],  xi[5],   C1, -S1);
    cmul(xr[9],  xi[9],    H,  -H);
    cmul(xr[13], xi[13],  S1, -C1);
    cmul(xr[6],  xi[6],    H,  -H);
    cmul(xr[10], xi[10], 0.f, -1.f);
    cmul(xr[14], xi[14],  -H,  -H);
    cmul(xr[7],  xi[7],   S1, -C1);
    cmul(xr[11], xi[11],  -H,  -H);
    cmul(xr[15], xi[15], -C1,  S1);
    #pragma unroll
    for (int g = 0; g < 4; ++g)
        bfly4_f(xr[4*g],xi[4*g], xr[4*g+1],xi[4*g+1], xr[4*g+2],xi[4*g+2], xr[4*g+3],xi[4*g+3]);
}

// In-place inverse DFT16 (unnormalized). Input: slot r holds X[REV(r)].
__device__ __forceinline__ void idft16(float xr[16], float xi[16]) {
    const float C1 = 0.9238795325112867f;
    const float S1 = 0.3826834323650898f;
    const float H  = 0.7071067811865476f;
    #pragma unroll
    for (int g = 0; g < 4; ++g)
        bfly4_i(xr[4*g],xi[4*g], xr[4*g+1],xi[4*g+1], xr[4*g+2],xi[4*g+2], xr[4*g+3],xi[4*g+3]);
    cmul(xr[5],  xi[5],   C1,  S1);
    cmul(xr[9],  xi[9],    H,   H);
    cmul(xr[13], xi[13],  S1,  C1);
    cmul(xr[6],  xi[6],    H,   H);
    cmul(xr[10], xi[10], 0.f, 1.f);
    cmul(xr[14], xi[14],  -H,   H);
    cmul(xr[7],  xi[7],   S1,  C1);
    cmul(xr[11], xi[11],  -H,   H);
    cmul(xr[15], xi[15], -C1, -S1);
    #pragma unroll
    for (int m = 0; m < 4; ++m)
        bfly4_i(xr[m],xi[m], xr[m+4],xi[m+4], xr[m+8],xi[m+8], xr[m+12],xi[m+12]);
}

// apply w^{REV(r)} to slot r; binary-power chain, dependency depth ~5.
__device__ __forceinline__ void twiddle_rev(float xr[16], float xi[16], float ang) {
    float s1, c1; __sincosf(ang, &s1, &c1);
    float c2 = c1*c1 - s1*s1, s2 = 2.f*c1*s1;
    float c3 = c2*c1 - s2*s1, s3 = c2*s1 + s2*c1;
    float c4 = c2*c2 - s2*s2, s4 = 2.f*c2*s2;
    cmul(xr[4],  xi[4],  c1, s1);
    cmul(xr[8],  xi[8],  c2, s2);
    cmul(xr[12], xi[12], c3, s3);
    float bc = c4, bs = s4;
    #pragma unroll
    for (int q = 1; q < 4; ++q) {
        cmul(xr[q], xi[q], bc, bs);
        { float ec = bc*c1 - bs*s1, es = bc*s1 + bs*c1; cmul(xr[4+q],  xi[4+q],  ec, es); }
        { float ec = bc*c2 - bs*s2, es = bc*s2 + bs*c2; cmul(xr[8+q],  xi[8+q],  ec, es); }
        { float ec = bc*c3 - bs*s3, es = bc*s3 + bs*c3; cmul(xr[12+q], xi[12+q], ec, es); }
        if (q < 3) { float nb = bc*c4 - bs*s4; bs = bc*s4 + bs*c4; bc = nb; }
    }
}

__global__ __launch_bounds__(THREADS, 4) void fourier_fft_kernel(
    const float* __restrict__ in, const float* __restrict__ gperm,
    const float* __restrict__ lw, float* __restrict__ out)
{
    __shared__ __align__(16) float re[PADN];
    __shared__ __align__(16) float im[PADN];
    const int t = threadIdx.x;
    const long long pair = blockIdx.x;
    const float* r0 = in + pair * (2LL * FFT_N);

    const float CFA = -6.28318530717958647692f / 4096.0f;
    const float CFB = -6.28318530717958647692f / 256.0f;

    // per-thread LDS bases (all per-k offsets are compile-time immediates)
    const int baseA = t + 4 * (t >> 6);                        // + 272k
    const int baseB = 272 * (t >> 4) + (t & 15);               // + 16k + 4*(k>>2)
    const int baseC = 16 * t + 4 * (t >> 2);                   // + n (16B-aligned)
    const int jb = t & 15;

    float xr[16], xi[16];

    // load: 4 base pointers per stream; all offsets (<=3072 B) fold to immediates
    {
        const float* a0 = r0 + t;
        const float* a1 = a0 + 1024;
        const float* a2 = a0 + 2048;
        const float* a3 = a0 + 3072;
        const float* b0 = r0 + FFT_N + t;
        const float* b1 = b0 + 1024;
        const float* b2 = b0 + 2048;
        const float* b3 = b0 + 3072;
        #pragma unroll
        for (int n = 0; n < 4; ++n) {
            xr[n]      = a0[256*n];  xi[n]      = b0[256*n];
            xr[n + 4]  = a1[256*n];  xi[n + 4]  = b1[256*n];
            xr[n + 8]  = a2[256*n];  xi[n + 8]  = b2[256*n];
            xr[n + 12] = a3[256*n];  xi[n + 12] = b3[256*n];
        }
    }

    // ---- forward stage A (L=4096, j=t): slot r holds A[REV(r)]
    dft16_f(xr, xi);
    twiddle_rev(xr, xi, CFA * (float)t);
    #pragma unroll
    for (int k = 0; k < 16; ++k) {
        re[baseA + 272*k] = xr[REV(k)];
        im[baseA + 272*k] = xi[REV(k)];
    }
    __syncthreads();

    // ---- forward stage B (L=256, j=t&15)
    #pragma unroll
    for (int n = 0; n < 16; ++n) {
        int s = baseB + 16*n + 4*(n>>2);
        xr[n] = re[s]; xi[n] = im[s];
    }
    dft16_f(xr, xi);
    twiddle_rev(xr, xi, CFB * (float)jb);
    #pragma unroll
    for (int k = 0; k < 16; ++k) {
        int s = baseB + 16*k + 4*(k>>2);
        re[s] = xr[REV(k)]; im[s] = xi[REV(k)];
    }
    __syncthreads();

    // ---- forward stage C + pointwise G + inverse stage C', all in registers.
    #pragma unroll
    for (int q = 0; q < 4; ++q) {
        float4 vr = *(const float4*)&re[baseC + 4*q];
        float4 vi = *(const float4*)&im[baseC + 4*q];
        xr[4*q+0] = vr.x; xr[4*q+1] = vr.y; xr[4*q+2] = vr.z; xr[4*q+3] = vr.w;
        xi[4*q+0] = vi.x; xi[4*q+1] = vi.y; xi[4*q+2] = vi.z; xi[4*q+3] = vi.w;
    }
    dft16_f(xr, xi);
    {
        const float4* gp = (const float4*)(gperm + 16*t);   // already REV-permuted
        #pragma unroll
        for (int q = 0; q < 4; ++q) {
            float4 g = gp[q];
            xr[4*q+0] *= g.x; xi[4*q+0] *= g.x;
            xr[4*q+1] *= g.y; xi[4*q+1] *= g.y;
            xr[4*q+2] *= g.z; xi[4*q+2] *= g.z;
            xr[4*q+3] *= g.w; xi[4*q+3] *= g.w;
        }
    }
    idft16(xr, xi);
    #pragma unroll
    for (int q = 0; q < 4; ++q) {
        *(float4*)&re[baseC + 4*q] = make_float4(xr[4*q+0], xr[4*q+1], xr[4*q+2], xr[4*q+3]);
        *(float4*)&im[baseC + 4*q] = make_float4(xi[4*q+0], xi[4*q+1], xi[4*q+2], xi[4*q+3]);
    }
    __syncthreads();

    // ---- inverse stage B': load digit-reversed, conj twiddle, idft16
    #pragma unroll
    for (int k = 0; k < 16; ++k) {
        int s = baseB + 16*k + 4*(k>>2);
        xr[REV(k)] = re[s]; xi[REV(k)] = im[s];
    }
    twiddle_rev(xr, xi, -CFB * (float)jb);
    idft16(xr, xi);
    #pragma unroll
    for (int n = 0; n < 16; ++n) {
        int s = baseB + 16*n + 4*(n>>2);
        re[s] = xr[n]; im[s] = xi[n];
    }
    __syncthreads();

    // ---- inverse stage A' + epilogue straight from registers
    #pragma unroll
    for (int k = 0; k < 16; ++k) {
        xr[REV(k)] = re[baseA + 272*k];
        xi[REV(k)] = im[baseA + 272*k];
    }
    twiddle_rev(xr, xi, -CFA * (float)t);
    idft16(xr, xi);

    {
        float* o0 = out + pair * (2LL * FFT_N);
        const float* w0 = lw + t;
        const float* w1 = w0 + 1024;
        const float* w2 = w0 + 2048;
        const float* w3 = w0 + 3072;
        float* s0 = o0 + t;
        float* s1 = s0 + 1024;
        float* s2 = s0 + 2048;
        float* s3 = s0 + 3072;
        float* u0 = o0 + FFT_N + t;
        float* u1 = u0 + 1024;
        float* u2 = u0 + 2048;
        float* u3 = u0 + 3072;
        #pragma unroll
        for (int n = 0; n < 4; ++n) {
            float l0 = w0[256*n], l1 = w1[256*n], l2 = w2[256*n], l3 = w3[256*n];
            s0[256*n] = fmaxf(xr[n]      * l0, 0.0f);
            s1[256*n] = fmaxf(xr[n + 4]  * l1, 0.0f);
            s2[256*n] = fmaxf(xr[n + 8]  * l2, 0.0f);
            s3[256*n] = fmaxf(xr[n + 12] * l3, 0.0f);
            u0[256*n] = fmaxf(xi[n]      * l0, 0.0f);
            u1[256*n] = fmaxf(xi[n + 4]  * l1, 0.0f);
            u2[256*n] = fmaxf(xi[n + 8]  * l2, 0.0f);
            u3[256*n] = fmaxf(xi[n + 12] * l3, 0.0f);
        }
    }
}

extern "C" void kernel_launch(void* const* d_in, const int* in_sizes, int n_in,
                              void* d_out, int out_size, void* d_ws, size_t ws_size,
                              hipStream_t stream) {
    const float* inputs = (const float*)d_in[0];
    const float* fw     = (const float*)d_in[1];
    const float* lw     = (const float*)d_in[2];
    float* out   = (float*)d_out;
    float* gperm = (float*)d_ws;   // 4096 floats = 16 KB scratch

    hipLaunchKernelGGL(setup_g_kernel, dim3(FFT_N / THREADS), dim3(THREADS), 0, stream,
                       fw, gperm);

    const int pairs = in_sizes[0] / (2 * FFT_N);   // 16384 rows -> 8192 pairs
    hipLaunchKernelGGL(fourier_fft_kernel, dim3(pairs), dim3(THREADS), 0, stream,
                       inputs, gperm, lw, out);
}